// Round 1
// baseline (87.071 us; speedup 1.0000x reference)
//
#include <hip/hip_runtime.h>

// Reprojection residual for bundle adjustment.
// Inputs (setup_inputs order):
//   d_in[0] observe : float32 [N_OBS, 2]
//   d_in[1] cidx    : int32   [N_OBS]
//   d_in[2] pidx    : int32   [N_OBS]
//   d_in[3] K       : float32 [N_CAMS, 3]   (focal, k1, k2)
//   d_in[4] C       : float32 [N_CAMS, 7]   (t.xyz, q.xyzw)
//   d_in[5] P       : float32 [N_PTS, 3]
// Output: float32 [N_OBS, 2]

__global__ __launch_bounds__(256) void reproj_kernel(
    const float2* __restrict__ observe,
    const int*    __restrict__ cidx,
    const int*    __restrict__ pidx,
    const float*  __restrict__ K,
    const float*  __restrict__ C,
    const float*  __restrict__ P,
    float2*       __restrict__ out,
    int n)
{
    int i      = blockIdx.x * blockDim.x + threadIdx.x;
    int stride = gridDim.x * blockDim.x;
    for (; i < n; i += stride) {
        int c = cidx[i];
        int p = pidx[i];

        // Gather point (12B, random within 6 MB -> L2/L3 hits)
        const float* Pp = P + 3 * p;
        float vx = Pp[0], vy = Pp[1], vz = Pp[2];

        // Gather camera extrinsics (28B, random within 56 KB -> L1 hits)
        const float* Cc = C + 7 * c;
        float tx = Cc[0], ty = Cc[1], tz = Cc[2];
        float qx = Cc[3], qy = Cc[4], qz = Cc[5], qw = Cc[6];

        // uv = cross(qv, v)
        float uvx = qy * vz - qz * vy;
        float uvy = qz * vx - qx * vz;
        float uvz = qx * vy - qy * vx;
        // uuv = cross(qv, uv)
        float uuvx = qy * uvz - qz * uvy;
        float uuvy = qz * uvx - qx * uvz;
        float uuvz = qx * uvy - qy * uvx;

        // cp = v + 2*(qw*uv + uuv) + t
        float cpx = vx + 2.0f * (qw * uvx + uuvx) + tx;
        float cpy = vy + 2.0f * (qw * uvy + uuvy) + ty;
        float cpz = vz + 2.0f * (qw * uvz + uuvz) + tz;

        // n = -cp.xy / cp.z
        float nx = -cpx / cpz;
        float ny = -cpy / cpz;
        float r  = nx * nx + ny * ny;

        // Gather intrinsics (12B, random within 24 KB -> L1 hits)
        const float* Kc = K + 3 * c;
        float focal = Kc[0], k1 = Kc[1], k2 = Kc[2];
        float dist  = 1.0f + k1 * r + k2 * r * r;
        float fd    = focal * dist;

        float2 ob = observe[i];
        out[i] = make_float2(fd * nx - ob.x, fd * ny - ob.y);
    }
}

extern "C" void kernel_launch(void* const* d_in, const int* in_sizes, int n_in,
                              void* d_out, int out_size, void* d_ws, size_t ws_size,
                              hipStream_t stream)
{
    const float2* observe = (const float2*)d_in[0];
    const int*    cidx    = (const int*)d_in[1];
    const int*    pidx    = (const int*)d_in[2];
    const float*  K       = (const float*)d_in[3];
    const float*  C       = (const float*)d_in[4];
    const float*  P       = (const float*)d_in[5];
    float2*       out     = (float2*)d_out;

    int n = in_sizes[1];               // N_OBS (cidx flat count)
    int block = 256;
    int grid  = (n + block - 1) / block;
    if (grid > 2048) grid = 2048;      // grid-stride the rest

    reproj_kernel<<<grid, block, 0, stream>>>(observe, cidx, pidx, K, C, P, out, n);
}